// Round 7
// baseline (2089.904 us; speedup 1.0000x reference)
//
#include <hip/hip_runtime.h>
#include <math.h>

#define N_NODES 600000
#define N_EDGES 2400000
#define HD 64
#define F_IN 128
#define LEADS 12
#define NUM_GRAPHS 50000
#define OUT_DIM 32
#define SCAN_BLOCKS 586  // ceil(600000/1024)

// native vector type for nontemporal builtins (HIP_vector_type is a class
// and is rejected by __builtin_nontemporal_*)
typedef float nf4 __attribute__((ext_vector_type(4)));

// ---------------- CSR build ----------------
__global__ __launch_bounds__(256) void k_zero(int* __restrict__ cnt) {
    int i = blockIdx.x * 256 + threadIdx.x;
    if (i < N_NODES) cnt[i] = 0;
}

// histogram AND per-edge rank (return value of the atomic). The atomic
// round-trip happens here once; k_fill no longer needs an atomic at all.
__global__ __launch_bounds__(256) void k_hist(const int* __restrict__ dst,
                                              int* __restrict__ cnt,
                                              int* __restrict__ rank) {
    int e = blockIdx.x * 256 + threadIdx.x;
    if (e < N_EDGES) rank[e] = atomicAdd(&cnt[dst[e]], 1);
}

__global__ __launch_bounds__(256) void k_scan1(const int* __restrict__ cnt,
                                               int* __restrict__ offs,
                                               int* __restrict__ bsum,
                                               float* __restrict__ dinv) {
    __shared__ int lds[256];
    int t = threadIdx.x;
    int base = blockIdx.x * 1024 + t * 4;
    int v[4];
#pragma unroll
    for (int j = 0; j < 4; ++j) v[j] = (base + j < N_NODES) ? cnt[base + j] : 0;
    // fused dinv: deg + self-loop
#pragma unroll
    for (int j = 0; j < 4; ++j)
        if (base + j < N_NODES) dinv[base + j] = rsqrtf((float)(v[j] + 1));
    int s = v[0] + v[1] + v[2] + v[3];
    lds[t] = s;
    __syncthreads();
    int val = s;
    for (int off = 1; off < 256; off <<= 1) {
        int other = (t >= off) ? lds[t - off] : 0;
        __syncthreads();
        val += other;
        lds[t] = val;
        __syncthreads();
    }
    if (t == 255) bsum[blockIdx.x] = val;
    int run = val - s;
#pragma unroll
    for (int j = 0; j < 4; ++j) {
        if (base + j < N_NODES) offs[base + j] = run;
        run += v[j];
    }
}

__global__ __launch_bounds__(256) void k_scan2(int* __restrict__ bsum) {
    __shared__ int lds[SCAN_BLOCKS];
    for (int i = threadIdx.x; i < SCAN_BLOCKS; i += 256) lds[i] = bsum[i];
    __syncthreads();
    if (threadIdx.x == 0) {
        int run = 0;
        for (int i = 0; i < SCAN_BLOCKS; ++i) {
            int c = lds[i];
            lds[i] = run;
            run += c;
        }
    }
    __syncthreads();
    for (int i = threadIdx.x; i < SCAN_BLOCKS; i += 256) bsum[i] = lds[i];
}

__global__ __launch_bounds__(256) void k_scan3(int* __restrict__ offs,
                                               const int* __restrict__ bsum) {
    int i = blockIdx.x * 256 + threadIdx.x;
    if (i < N_NODES) offs[i] += bsum[i >> 10];
}

// atomic-free fill: position = segment base + precomputed rank.
__global__ __launch_bounds__(256) void k_fill(const int* __restrict__ src,
                                              const int* __restrict__ dst,
                                              const int* __restrict__ rank,
                                              const int* __restrict__ offs,
                                              int* __restrict__ eidx) {
    int e = blockIdx.x * 256 + threadIdx.x;
    if (e < N_EDGES) {
        int p = offs[dst[e]] + rank[e];
        eidx[p] = src[e];
    }
}

// ---------------- latency-optimized per-node edge gather ----------------
// 16-lane group accumulates 64 feature floats (float4/lane) over the node's
// edge list. Edge indices are prefetched coalesced; 8 row-loads in flight,
// branch-free masked fallback to the node's own (L1-hot) row.
__device__ __forceinline__ float4 gcn_gather(const float4* __restrict__ tp4,
                                             const int* __restrict__ eidx,
                                             int node, int start, int c, int cm,
                                             int sl, int grpBase) {
    float4 a0 = tp4[(size_t)node * 16 + sl];  // self-loop
    float4 a1 = {0.0f, 0.0f, 0.0f, 0.0f};
    float4 a2 = {0.0f, 0.0f, 0.0f, 0.0f};
    float4 a3 = {0.0f, 0.0f, 0.0f, 0.0f};

    for (int base = 0; base < cm; base += 16) {
        int idxreg = (base + sl < c) ? eidx[start + base + sl] : node;
        int take = cm - base;
        if (take > 16) take = 16;
        for (int j = 0; j < take; j += 8) {
            int i0 = __shfl(idxreg, grpBase + j + 0);
            int i1 = __shfl(idxreg, grpBase + j + 1);
            int i2 = __shfl(idxreg, grpBase + j + 2);
            int i3 = __shfl(idxreg, grpBase + j + 3);
            int i4 = __shfl(idxreg, grpBase + j + 4);
            int i5 = __shfl(idxreg, grpBase + j + 5);
            int i6 = __shfl(idxreg, grpBase + j + 6);
            int i7 = __shfl(idxreg, grpBase + j + 7);
            float m0 = (base + j + 0 < c) ? 1.0f : 0.0f;
            float m1 = (base + j + 1 < c) ? 1.0f : 0.0f;
            float m2 = (base + j + 2 < c) ? 1.0f : 0.0f;
            float m3 = (base + j + 3 < c) ? 1.0f : 0.0f;
            float m4 = (base + j + 4 < c) ? 1.0f : 0.0f;
            float m5 = (base + j + 5 < c) ? 1.0f : 0.0f;
            float m6 = (base + j + 6 < c) ? 1.0f : 0.0f;
            float m7 = (base + j + 7 < c) ? 1.0f : 0.0f;
            float4 v0 = tp4[(size_t)i0 * 16 + sl];
            float4 v1 = tp4[(size_t)i1 * 16 + sl];
            float4 v2 = tp4[(size_t)i2 * 16 + sl];
            float4 v3 = tp4[(size_t)i3 * 16 + sl];
            float4 v4 = tp4[(size_t)i4 * 16 + sl];
            float4 v5 = tp4[(size_t)i5 * 16 + sl];
            float4 v6 = tp4[(size_t)i6 * 16 + sl];
            float4 v7 = tp4[(size_t)i7 * 16 + sl];
            a0.x = fmaf(m0, v0.x, a0.x); a0.y = fmaf(m0, v0.y, a0.y);
            a0.z = fmaf(m0, v0.z, a0.z); a0.w = fmaf(m0, v0.w, a0.w);
            a1.x = fmaf(m1, v1.x, a1.x); a1.y = fmaf(m1, v1.y, a1.y);
            a1.z = fmaf(m1, v1.z, a1.z); a1.w = fmaf(m1, v1.w, a1.w);
            a2.x = fmaf(m2, v2.x, a2.x); a2.y = fmaf(m2, v2.y, a2.y);
            a2.z = fmaf(m2, v2.z, a2.z); a2.w = fmaf(m2, v2.w, a2.w);
            a3.x = fmaf(m3, v3.x, a3.x); a3.y = fmaf(m3, v3.y, a3.y);
            a3.z = fmaf(m3, v3.z, a3.z); a3.w = fmaf(m3, v3.w, a3.w);
            a0.x = fmaf(m4, v4.x, a0.x); a0.y = fmaf(m4, v4.y, a0.y);
            a0.z = fmaf(m4, v4.z, a0.z); a0.w = fmaf(m4, v4.w, a0.w);
            a1.x = fmaf(m5, v5.x, a1.x); a1.y = fmaf(m5, v5.y, a1.y);
            a1.z = fmaf(m5, v5.z, a1.z); a1.w = fmaf(m5, v5.w, a1.w);
            a2.x = fmaf(m6, v6.x, a2.x); a2.y = fmaf(m6, v6.y, a2.y);
            a2.z = fmaf(m6, v6.z, a2.z); a2.w = fmaf(m6, v6.w, a2.w);
            a3.x = fmaf(m7, v7.x, a3.x); a3.y = fmaf(m7, v7.y, a3.y);
            a3.z = fmaf(m7, v7.z, a3.z); a3.w = fmaf(m7, v7.w, a3.w);
        }
    }
    a0.x += a1.x + a2.x + a3.x;
    a0.y += a1.y + a2.y + a3.y;
    a0.z += a1.z + a2.z + a3.z;
    a0.w += a1.w + a2.w + a3.w;
    return a0;
}

// ---------------- GEMM: lane=row, scalar W, 16 cols per wave --------------------
template <int K>
__global__ __launch_bounds__(256) void k_gemm(const float* __restrict__ in,
                                              const float* __restrict__ W,
                                              const float* __restrict__ dinv,
                                              float* __restrict__ tout) {
    __shared__ float lx[64 * (K + 1)];
    const int t = threadIdx.x;
    const int lane = t & 63;
    const int r0 = blockIdx.x * 64;

#pragma unroll
    for (int i = 0; i < K / 16; ++i) {
        int f = (t + i * 256) * 4;
        int r = f / K, k = f % K;
        nf4 v = __builtin_nontemporal_load(
            (const nf4*)(in + (size_t)(r0 + r) * K + k));
        float* p = &lx[r * (K + 1) + k];
        p[0] = v.x; p[1] = v.y; p[2] = v.z; p[3] = v.w;
    }
    __syncthreads();

    const int c0 = __builtin_amdgcn_readfirstlane((t >> 6) * 16);
    const float* Wp = W + c0;

    float acc[16];
#pragma unroll
    for (int cc = 0; cc < 16; ++cc) acc[cc] = 0.0f;

#pragma unroll
    for (int k = 0; k < K; ++k) {
        float xk = lx[lane * (K + 1) + k];
#pragma unroll
        for (int cc = 0; cc < 16; ++cc)
            acc[cc] = fmaf(xk, Wp[k * HD + cc], acc[cc]);  // SGPR operand
    }

    float di = dinv[r0 + lane];
#pragma unroll
    for (int cc = 0; cc < 16; ++cc) acc[cc] *= di;

    __syncthreads();
#pragma unroll
    for (int cc = 0; cc < 16; ++cc) lx[lane * 65 + c0 + cc] = acc[cc];
    __syncthreads();

    const int w = t >> 6;
#pragma unroll
    for (int i = 0; i < 16; ++i) {
        int r = i * 4 + w;
        tout[(size_t)(r0 + r) * HD + lane] = lx[r * 65 + lane];
    }
}

// ---------------- fused gather(layer i) + gemm(layer i+1) ----------------
__global__ __launch_bounds__(256) void k_fused(const float* __restrict__ tp,
                                               const int* __restrict__ eidx,
                                               const int* __restrict__ offs,
                                               const int* __restrict__ cnt,
                                               const float* __restrict__ dinv,
                                               const float* __restrict__ bias,
                                               const float* __restrict__ W,
                                               float* __restrict__ tout) {
    __shared__ float lhx[64 * 65];
    const int t = threadIdx.x;
    const int lane = t & 63;
    const int w = t >> 6;
    const int r0 = blockIdx.x * 64;
    const int grp = lane >> 4, sl = lane & 15;
    const int grpBase = lane & 48;

    const float4* tp4 = (const float4*)tp;
    const float4 b4 = *(const float4*)(bias + sl * 4);

#pragma unroll
    for (int p = 0; p < 4; ++p) {
        const int nl = p * 16 + w * 4 + grp;
        const int node = r0 + nl;

        const int start = offs[node];
        const int c = cnt[node];

        int cm = c;
#pragma unroll
        for (int off = 32; off >= 1; off >>= 1) cm = max(cm, __shfl_xor(cm, off));

        float4 r = gcn_gather(tp4, eidx, node, start, c, cm, sl, grpBase);

        const float di = dinv[node];
        float* pl = &lhx[nl * 65 + sl * 4];
        pl[0] = fmaxf(fmaf(di, r.x, b4.x), 0.0f);
        pl[1] = fmaxf(fmaf(di, r.y, b4.y), 0.0f);
        pl[2] = fmaxf(fmaf(di, r.z, b4.z), 0.0f);
        pl[3] = fmaxf(fmaf(di, r.w, b4.w), 0.0f);
    }
    __syncthreads();

    const int c0 = __builtin_amdgcn_readfirstlane(w * 16);
    const float* Wp = W + c0;

    float acc[16];
#pragma unroll
    for (int cc = 0; cc < 16; ++cc) acc[cc] = 0.0f;

#pragma unroll
    for (int k = 0; k < HD; ++k) {
        float xk = lhx[lane * 65 + k];
#pragma unroll
        for (int cc = 0; cc < 16; ++cc)
            acc[cc] = fmaf(xk, Wp[k * HD + cc], acc[cc]);
    }

    float di2 = dinv[r0 + lane];  // source-side scale for NEXT aggregation
#pragma unroll
    for (int cc = 0; cc < 16; ++cc) acc[cc] *= di2;

    __syncthreads();
#pragma unroll
    for (int cc = 0; cc < 16; ++cc) lhx[lane * 65 + c0 + cc] = acc[cc];
    __syncthreads();

#pragma unroll
    for (int i = 0; i < 16; ++i) {
        int r = i * 4 + w;
        __builtin_nontemporal_store(lhx[r * 65 + lane],
                                    &tout[(size_t)(r0 + r) * HD + lane]);
    }
}

// ---------------- fused layer-3 gather + attention-score GEMM ----------------
// Gather phase fills lhx with final h3 rows (di*agg + b3, relu). Then the
// k_gemm SGPR pattern computes energy = tanh(h@Wa) and its dot with v,
// reduced across the 4 waves -> per-node score s. h3 rows are written with
// NORMAL stores (write-allocate) so k_pool reads them from L3.
__global__ __launch_bounds__(256) void k_fused3(const float* __restrict__ tp,
                                                const int* __restrict__ eidx,
                                                const int* __restrict__ offs,
                                                const int* __restrict__ cnt,
                                                const float* __restrict__ dinv,
                                                const float* __restrict__ bias,
                                                const float* __restrict__ Wa,
                                                const float* __restrict__ vvec,
                                                float* __restrict__ hout,
                                                float* __restrict__ sout) {
    __shared__ float lhx[64 * 65];
    __shared__ float sp[4][64];
    const int t = threadIdx.x;
    const int lane = t & 63;
    const int w = t >> 6;
    const int r0 = blockIdx.x * 64;
    const int grp = lane >> 4, sl = lane & 15;
    const int grpBase = lane & 48;

    const float4* tp4 = (const float4*)tp;
    const float4 b4 = *(const float4*)(bias + sl * 4);

#pragma unroll
    for (int p = 0; p < 4; ++p) {
        const int nl = p * 16 + w * 4 + grp;
        const int node = r0 + nl;

        const int start = offs[node];
        const int c = cnt[node];

        int cm = c;
#pragma unroll
        for (int off = 32; off >= 1; off >>= 1) cm = max(cm, __shfl_xor(cm, off));

        float4 r = gcn_gather(tp4, eidx, node, start, c, cm, sl, grpBase);

        const float di = dinv[node];
        float* pl = &lhx[nl * 65 + sl * 4];
        pl[0] = fmaxf(fmaf(di, r.x, b4.x), 0.0f);
        pl[1] = fmaxf(fmaf(di, r.y, b4.y), 0.0f);
        pl[2] = fmaxf(fmaf(di, r.z, b4.z), 0.0f);
        pl[3] = fmaxf(fmaf(di, r.w, b4.w), 0.0f);
    }
    __syncthreads();

    // energy GEMM: row = lane, cols [c0, c0+16) per wave, W via s_load
    const int c0 = __builtin_amdgcn_readfirstlane(w * 16);
    const float* Wp = Wa + c0;

    float acc[16];
#pragma unroll
    for (int cc = 0; cc < 16; ++cc) acc[cc] = 0.0f;

#pragma unroll
    for (int k = 0; k < HD; ++k) {
        float xk = lhx[lane * 65 + k];
#pragma unroll
        for (int cc = 0; cc < 16; ++cc)
            acc[cc] = fmaf(xk, Wp[k * HD + cc], acc[cc]);
    }

    // partial score = sum_cc tanh(acc)*v[c0+cc]  (v via s_load, uniform)
    float part = 0.0f;
#pragma unroll
    for (int cc = 0; cc < 16; ++cc)
        part = fmaf(tanhf(acc[cc]), vvec[c0 + cc], part);
    sp[w][lane] = part;
    __syncthreads();

    // write h3 rows (normal store -> L3-resident for k_pool)
#pragma unroll
    for (int i = 0; i < 16; ++i) {
        int r = i * 4 + w;
        hout[(size_t)(r0 + r) * HD + lane] = lhx[r * 65 + lane];
    }

    if (w == 0) {
        float s = sp[0][lane] + sp[1][lane] + sp[2][lane] + sp[3][lane];
        sout[r0 + lane] = s;
    }
}

// ---------------- softmax + pool + linear (1 wave per graph) ----------------
__global__ __launch_bounds__(256) void k_pool(const float* __restrict__ h3,
                                              const float* __restrict__ s,
                                              const float* __restrict__ Wl,
                                              const float* __restrict__ bl,
                                              float* __restrict__ out,
                                              float* __restrict__ lw) {
    __shared__ float lds_Wl[128 * 32];
    __shared__ float lds_p[4][128];
    const int t = threadIdx.x;
    const int lane = t & 63;
    const int wid = t >> 6;

#pragma unroll
    for (int i = 0; i < 16; ++i) lds_Wl[t + i * 256] = Wl[t + i * 256];
    __syncthreads();

    const int g = blockIdx.x * 4 + wid;

    // softmax over the 12 lead scores (lanes >=12 padded)
    float sv = (lane < LEADS) ? s[g * LEADS + lane] : -1e30f;
    float m = sv;
#pragma unroll
    for (int off = 32; off >= 1; off >>= 1) m = fmaxf(m, __shfl_xor(m, off));
    float e = (lane < LEADS) ? expf(sv - m) : 0.0f;
    float sum = e;
#pragma unroll
    for (int off = 32; off >= 1; off >>= 1) sum += __shfl_xor(sum, off);
    float inv = 1.0f / sum;

    if (lane < LEADS) lw[g * LEADS + lane] = e * inv;

    // weighted max/mean pool; lane = feature channel
    float gmax = -1e30f, gsum = 0.0f;
#pragma unroll
    for (int r = 0; r < LEADS; ++r) {
        float wr = __shfl(e, r) * inv;  // graph-uniform weight
        float hv = h3[(size_t)(g * LEADS + r) * HD + lane];
        float wh = hv * wr;
        gmax = fmaxf(gmax, wh);
        gsum += wh;
    }
    lds_p[wid][lane] = gmax;
    lds_p[wid][64 + lane] = gsum * (1.0f / 12.0f);

    int o = lane & 31, half = lane >> 5;
    float acc2 = 0.0f;
#pragma unroll
    for (int k = 0; k < 64; ++k) {
        int kk = half * 64 + k;
        acc2 = fmaf(lds_p[wid][kk], lds_Wl[kk * 32 + o], acc2);
    }
    acc2 += __shfl_xor(acc2, 32);
    if (lane < 32) out[g * 32 + lane] = fmaxf(acc2 + bl[lane], 0.0f);
}

// ---------------- launch ----------------
extern "C" void kernel_launch(void* const* d_in, const int* in_sizes, int n_in,
                              void* d_out, int out_size, void* d_ws, size_t ws_size,
                              hipStream_t stream) {
    const float* x  = (const float*)d_in[0];
    const int* ei   = (const int*)d_in[1];
    const int* src  = ei;
    const int* dst  = ei + N_EDGES;
    const float* W1 = (const float*)d_in[3];
    const float* b1 = (const float*)d_in[4];
    const float* W2 = (const float*)d_in[5];
    const float* b2 = (const float*)d_in[6];
    const float* W3 = (const float*)d_in[7];
    const float* b3 = (const float*)d_in[8];
    const float* Wa = (const float*)d_in[9];
    const float* vv = (const float*)d_in[10];
    const float* Wl = (const float*)d_in[11];
    const float* bl = (const float*)d_in[12];

    float* out = (float*)d_out;
    float* lw  = out + (size_t)NUM_GRAPHS * 32;

    float* dinv = (float*)d_ws;                       // N f32
    int* cnt    = (int*)(dinv + N_NODES);             // N
    int* offs   = cnt + N_NODES;                      // N
    int* bsum   = offs + N_NODES;                     // 1024
    int* eidx   = bsum + 1024;                        // E
    float* T    = (float*)(eidx + N_EDGES);           // N*64
    float* Hb   = T + (size_t)N_NODES * HD;           // N*64
    float* S    = Hb + (size_t)N_NODES * HD;          // N (attention scores)
    // rank aliases T: T is first written by k_gemm, strictly after k_fill
    // consumed rank (in-order stream).
    int* rank   = (int*)T;                            // E (aliased)

    const int gN = (N_NODES + 255) / 256;
    const int gE = (N_EDGES + 255) / 256;

    k_zero<<<gN, 256, 0, stream>>>(cnt);
    k_hist<<<gE, 256, 0, stream>>>(dst, cnt, rank);
    k_scan1<<<SCAN_BLOCKS, 256, 0, stream>>>(cnt, offs, bsum, dinv);
    k_scan2<<<1, 256, 0, stream>>>(bsum);
    k_scan3<<<gN, 256, 0, stream>>>(offs, bsum);
    k_fill<<<gE, 256, 0, stream>>>(src, dst, rank, offs, eidx);

    // layer 1 transform: T1 = dinv * (x @ W1)
    k_gemm<128><<<N_NODES / 64, 256, 0, stream>>>(x, W1, dinv, T);
    // fused: h1 = relu(agg(T1)+b1) in LDS; T2 = dinv * (h1 @ W2)
    k_fused<<<N_NODES / 64, 256, 0, stream>>>(T, eidx, offs, cnt, dinv, b1, W2, Hb);
    // fused: h2 = relu(agg(T2)+b2) in LDS; T3 = dinv * (h2 @ W3)
    k_fused<<<N_NODES / 64, 256, 0, stream>>>(Hb, eidx, offs, cnt, dinv, b2, W3, T);
    // fused: h3 = relu(agg(T3)+b3) in LDS; s = tanh(h3@Wa)@v; write h3 + s
    k_fused3<<<N_NODES / 64, 256, 0, stream>>>(T, eidx, offs, cnt, dinv, b3,
                                               Wa, vv, Hb, S);
    // per-graph softmax + pool + linear
    k_pool<<<NUM_GRAPHS / 4, 256, 0, stream>>>(Hb, S, Wl, bl, out, lw);
}

// Round 8
// 1190.764 us; speedup vs baseline: 1.7551x; 1.7551x over previous
//
#include <hip/hip_runtime.h>
#include <math.h>

#define N_NODES 600000
#define N_EDGES 2400000
#define HD 64
#define F_IN 128
#define LEADS 12
#define NUM_GRAPHS 50000
#define OUT_DIM 32
#define SCAN_BLOCKS 586  // ceil(600000/1024)

// native vector type for nontemporal builtins (HIP_vector_type is a class
// and is rejected by __builtin_nontemporal_*)
typedef float nf4 __attribute__((ext_vector_type(4)));

// fast tanh from hardware ops: v_exp_f32 (2^x) + v_rcp_f32.
// tanh(x) = 1 - 2/(exp2(x*2*log2e)+1); saturates correctly (exp2->inf/0).
// ~1e-6 abs error, vs 4.9e-4 harness tolerance. Avoids __ocml_tanh_f32's
// opaque multi-branch expansion (the round-7 VALU blowup: 96% VALUBusy).
__device__ __forceinline__ float fast_tanh(float x) {
    float e = __builtin_amdgcn_exp2f(x * 2.8853900817779268f);
    return 1.0f - 2.0f * __builtin_amdgcn_rcpf(e + 1.0f);
}

// ---------------- CSR build ----------------
__global__ __launch_bounds__(256) void k_zero(int* __restrict__ cnt) {
    int i = blockIdx.x * 256 + threadIdx.x;
    if (i < N_NODES) cnt[i] = 0;
}

// histogram AND per-edge rank (return value of the atomic). The atomic
// round-trip happens here once; k_fill no longer needs an atomic at all.
__global__ __launch_bounds__(256) void k_hist(const int* __restrict__ dst,
                                              int* __restrict__ cnt,
                                              int* __restrict__ rank) {
    int e = blockIdx.x * 256 + threadIdx.x;
    if (e < N_EDGES) rank[e] = atomicAdd(&cnt[dst[e]], 1);
}

__global__ __launch_bounds__(256) void k_scan1(const int* __restrict__ cnt,
                                               int* __restrict__ offs,
                                               int* __restrict__ bsum,
                                               float* __restrict__ dinv) {
    __shared__ int lds[256];
    int t = threadIdx.x;
    int base = blockIdx.x * 1024 + t * 4;
    int v[4];
#pragma unroll
    for (int j = 0; j < 4; ++j) v[j] = (base + j < N_NODES) ? cnt[base + j] : 0;
    // fused dinv: deg + self-loop
#pragma unroll
    for (int j = 0; j < 4; ++j)
        if (base + j < N_NODES) dinv[base + j] = rsqrtf((float)(v[j] + 1));
    int s = v[0] + v[1] + v[2] + v[3];
    lds[t] = s;
    __syncthreads();
    int val = s;
    for (int off = 1; off < 256; off <<= 1) {
        int other = (t >= off) ? lds[t - off] : 0;
        __syncthreads();
        val += other;
        lds[t] = val;
        __syncthreads();
    }
    if (t == 255) bsum[blockIdx.x] = val;
    int run = val - s;
#pragma unroll
    for (int j = 0; j < 4; ++j) {
        if (base + j < N_NODES) offs[base + j] = run;
        run += v[j];
    }
}

__global__ __launch_bounds__(256) void k_scan2(int* __restrict__ bsum) {
    __shared__ int lds[SCAN_BLOCKS];
    for (int i = threadIdx.x; i < SCAN_BLOCKS; i += 256) lds[i] = bsum[i];
    __syncthreads();
    if (threadIdx.x == 0) {
        int run = 0;
        for (int i = 0; i < SCAN_BLOCKS; ++i) {
            int c = lds[i];
            lds[i] = run;
            run += c;
        }
    }
    __syncthreads();
    for (int i = threadIdx.x; i < SCAN_BLOCKS; i += 256) bsum[i] = lds[i];
}

__global__ __launch_bounds__(256) void k_scan3(int* __restrict__ offs,
                                               const int* __restrict__ bsum) {
    int i = blockIdx.x * 256 + threadIdx.x;
    if (i < N_NODES) offs[i] += bsum[i >> 10];
}

// atomic-free fill: position = segment base + precomputed rank.
__global__ __launch_bounds__(256) void k_fill(const int* __restrict__ src,
                                              const int* __restrict__ dst,
                                              const int* __restrict__ rank,
                                              const int* __restrict__ offs,
                                              int* __restrict__ eidx) {
    int e = blockIdx.x * 256 + threadIdx.x;
    if (e < N_EDGES) {
        int p = offs[dst[e]] + rank[e];
        eidx[p] = src[e];
    }
}

// ---------------- latency-optimized per-node edge gather ----------------
__device__ __forceinline__ float4 gcn_gather(const float4* __restrict__ tp4,
                                             const int* __restrict__ eidx,
                                             int node, int start, int c, int cm,
                                             int sl, int grpBase) {
    float4 a0 = tp4[(size_t)node * 16 + sl];  // self-loop
    float4 a1 = {0.0f, 0.0f, 0.0f, 0.0f};
    float4 a2 = {0.0f, 0.0f, 0.0f, 0.0f};
    float4 a3 = {0.0f, 0.0f, 0.0f, 0.0f};

    for (int base = 0; base < cm; base += 16) {
        int idxreg = (base + sl < c) ? eidx[start + base + sl] : node;
        int take = cm - base;
        if (take > 16) take = 16;
        for (int j = 0; j < take; j += 8) {
            int i0 = __shfl(idxreg, grpBase + j + 0);
            int i1 = __shfl(idxreg, grpBase + j + 1);
            int i2 = __shfl(idxreg, grpBase + j + 2);
            int i3 = __shfl(idxreg, grpBase + j + 3);
            int i4 = __shfl(idxreg, grpBase + j + 4);
            int i5 = __shfl(idxreg, grpBase + j + 5);
            int i6 = __shfl(idxreg, grpBase + j + 6);
            int i7 = __shfl(idxreg, grpBase + j + 7);
            float m0 = (base + j + 0 < c) ? 1.0f : 0.0f;
            float m1 = (base + j + 1 < c) ? 1.0f : 0.0f;
            float m2 = (base + j + 2 < c) ? 1.0f : 0.0f;
            float m3 = (base + j + 3 < c) ? 1.0f : 0.0f;
            float m4 = (base + j + 4 < c) ? 1.0f : 0.0f;
            float m5 = (base + j + 5 < c) ? 1.0f : 0.0f;
            float m6 = (base + j + 6 < c) ? 1.0f : 0.0f;
            float m7 = (base + j + 7 < c) ? 1.0f : 0.0f;
            float4 v0 = tp4[(size_t)i0 * 16 + sl];
            float4 v1 = tp4[(size_t)i1 * 16 + sl];
            float4 v2 = tp4[(size_t)i2 * 16 + sl];
            float4 v3 = tp4[(size_t)i3 * 16 + sl];
            float4 v4 = tp4[(size_t)i4 * 16 + sl];
            float4 v5 = tp4[(size_t)i5 * 16 + sl];
            float4 v6 = tp4[(size_t)i6 * 16 + sl];
            float4 v7 = tp4[(size_t)i7 * 16 + sl];
            a0.x = fmaf(m0, v0.x, a0.x); a0.y = fmaf(m0, v0.y, a0.y);
            a0.z = fmaf(m0, v0.z, a0.z); a0.w = fmaf(m0, v0.w, a0.w);
            a1.x = fmaf(m1, v1.x, a1.x); a1.y = fmaf(m1, v1.y, a1.y);
            a1.z = fmaf(m1, v1.z, a1.z); a1.w = fmaf(m1, v1.w, a1.w);
            a2.x = fmaf(m2, v2.x, a2.x); a2.y = fmaf(m2, v2.y, a2.y);
            a2.z = fmaf(m2, v2.z, a2.z); a2.w = fmaf(m2, v2.w, a2.w);
            a3.x = fmaf(m3, v3.x, a3.x); a3.y = fmaf(m3, v3.y, a3.y);
            a3.z = fmaf(m3, v3.z, a3.z); a3.w = fmaf(m3, v3.w, a3.w);
            a0.x = fmaf(m4, v4.x, a0.x); a0.y = fmaf(m4, v4.y, a0.y);
            a0.z = fmaf(m4, v4.z, a0.z); a0.w = fmaf(m4, v4.w, a0.w);
            a1.x = fmaf(m5, v5.x, a1.x); a1.y = fmaf(m5, v5.y, a1.y);
            a1.z = fmaf(m5, v5.z, a1.z); a1.w = fmaf(m5, v5.w, a1.w);
            a2.x = fmaf(m6, v6.x, a2.x); a2.y = fmaf(m6, v6.y, a2.y);
            a2.z = fmaf(m6, v6.z, a2.z); a2.w = fmaf(m6, v6.w, a2.w);
            a3.x = fmaf(m7, v7.x, a3.x); a3.y = fmaf(m7, v7.y, a3.y);
            a3.z = fmaf(m7, v7.z, a3.z); a3.w = fmaf(m7, v7.w, a3.w);
        }
    }
    a0.x += a1.x + a2.x + a3.x;
    a0.y += a1.y + a2.y + a3.y;
    a0.z += a1.z + a2.z + a3.z;
    a0.w += a1.w + a2.w + a3.w;
    return a0;
}

// ---------------- GEMM: lane=row, scalar W, 16 cols per wave --------------------
template <int K>
__global__ __launch_bounds__(256) void k_gemm(const float* __restrict__ in,
                                              const float* __restrict__ W,
                                              const float* __restrict__ dinv,
                                              float* __restrict__ tout) {
    __shared__ float lx[64 * (K + 1)];
    const int t = threadIdx.x;
    const int lane = t & 63;
    const int r0 = blockIdx.x * 64;

#pragma unroll
    for (int i = 0; i < K / 16; ++i) {
        int f = (t + i * 256) * 4;
        int r = f / K, k = f % K;
        nf4 v = __builtin_nontemporal_load(
            (const nf4*)(in + (size_t)(r0 + r) * K + k));
        float* p = &lx[r * (K + 1) + k];
        p[0] = v.x; p[1] = v.y; p[2] = v.z; p[3] = v.w;
    }
    __syncthreads();

    const int c0 = __builtin_amdgcn_readfirstlane((t >> 6) * 16);
    const float* Wp = W + c0;

    float acc[16];
#pragma unroll
    for (int cc = 0; cc < 16; ++cc) acc[cc] = 0.0f;

#pragma unroll
    for (int k = 0; k < K; ++k) {
        float xk = lx[lane * (K + 1) + k];
#pragma unroll
        for (int cc = 0; cc < 16; ++cc)
            acc[cc] = fmaf(xk, Wp[k * HD + cc], acc[cc]);  // SGPR operand
    }

    float di = dinv[r0 + lane];
#pragma unroll
    for (int cc = 0; cc < 16; ++cc) acc[cc] *= di;

    __syncthreads();
#pragma unroll
    for (int cc = 0; cc < 16; ++cc) lx[lane * 65 + c0 + cc] = acc[cc];
    __syncthreads();

    const int w = t >> 6;
#pragma unroll
    for (int i = 0; i < 16; ++i) {
        int r = i * 4 + w;
        tout[(size_t)(r0 + r) * HD + lane] = lx[r * 65 + lane];
    }
}

// ---------------- fused gather(layer i) + gemm(layer i+1) ----------------
__global__ __launch_bounds__(256) void k_fused(const float* __restrict__ tp,
                                               const int* __restrict__ eidx,
                                               const int* __restrict__ offs,
                                               const int* __restrict__ cnt,
                                               const float* __restrict__ dinv,
                                               const float* __restrict__ bias,
                                               const float* __restrict__ W,
                                               float* __restrict__ tout) {
    __shared__ float lhx[64 * 65];
    const int t = threadIdx.x;
    const int lane = t & 63;
    const int w = t >> 6;
    const int r0 = blockIdx.x * 64;
    const int grp = lane >> 4, sl = lane & 15;
    const int grpBase = lane & 48;

    const float4* tp4 = (const float4*)tp;
    const float4 b4 = *(const float4*)(bias + sl * 4);

#pragma unroll
    for (int p = 0; p < 4; ++p) {
        const int nl = p * 16 + w * 4 + grp;
        const int node = r0 + nl;

        const int start = offs[node];
        const int c = cnt[node];

        int cm = c;
#pragma unroll
        for (int off = 32; off >= 1; off >>= 1) cm = max(cm, __shfl_xor(cm, off));

        float4 r = gcn_gather(tp4, eidx, node, start, c, cm, sl, grpBase);

        const float di = dinv[node];
        float* pl = &lhx[nl * 65 + sl * 4];
        pl[0] = fmaxf(fmaf(di, r.x, b4.x), 0.0f);
        pl[1] = fmaxf(fmaf(di, r.y, b4.y), 0.0f);
        pl[2] = fmaxf(fmaf(di, r.z, b4.z), 0.0f);
        pl[3] = fmaxf(fmaf(di, r.w, b4.w), 0.0f);
    }
    __syncthreads();

    const int c0 = __builtin_amdgcn_readfirstlane(w * 16);
    const float* Wp = W + c0;

    float acc[16];
#pragma unroll
    for (int cc = 0; cc < 16; ++cc) acc[cc] = 0.0f;

#pragma unroll
    for (int k = 0; k < HD; ++k) {
        float xk = lhx[lane * 65 + k];
#pragma unroll
        for (int cc = 0; cc < 16; ++cc)
            acc[cc] = fmaf(xk, Wp[k * HD + cc], acc[cc]);
    }

    float di2 = dinv[r0 + lane];  // source-side scale for NEXT aggregation
#pragma unroll
    for (int cc = 0; cc < 16; ++cc) acc[cc] *= di2;

    __syncthreads();
#pragma unroll
    for (int cc = 0; cc < 16; ++cc) lhx[lane * 65 + c0 + cc] = acc[cc];
    __syncthreads();

#pragma unroll
    for (int i = 0; i < 16; ++i) {
        int r = i * 4 + w;
        __builtin_nontemporal_store(lhx[r * 65 + lane],
                                    &tout[(size_t)(r0 + r) * HD + lane]);
    }
}

// ---------------- fused layer-3 gather + attention-score GEMM ----------------
__global__ __launch_bounds__(256) void k_fused3(const float* __restrict__ tp,
                                                const int* __restrict__ eidx,
                                                const int* __restrict__ offs,
                                                const int* __restrict__ cnt,
                                                const float* __restrict__ dinv,
                                                const float* __restrict__ bias,
                                                const float* __restrict__ Wa,
                                                const float* __restrict__ vvec,
                                                float* __restrict__ hout,
                                                float* __restrict__ sout) {
    __shared__ float lhx[64 * 65];
    __shared__ float sp[4][64];
    const int t = threadIdx.x;
    const int lane = t & 63;
    const int w = t >> 6;
    const int r0 = blockIdx.x * 64;
    const int grp = lane >> 4, sl = lane & 15;
    const int grpBase = lane & 48;

    const float4* tp4 = (const float4*)tp;
    const float4 b4 = *(const float4*)(bias + sl * 4);

#pragma unroll
    for (int p = 0; p < 4; ++p) {
        const int nl = p * 16 + w * 4 + grp;
        const int node = r0 + nl;

        const int start = offs[node];
        const int c = cnt[node];

        int cm = c;
#pragma unroll
        for (int off = 32; off >= 1; off >>= 1) cm = max(cm, __shfl_xor(cm, off));

        float4 r = gcn_gather(tp4, eidx, node, start, c, cm, sl, grpBase);

        const float di = dinv[node];
        float* pl = &lhx[nl * 65 + sl * 4];
        pl[0] = fmaxf(fmaf(di, r.x, b4.x), 0.0f);
        pl[1] = fmaxf(fmaf(di, r.y, b4.y), 0.0f);
        pl[2] = fmaxf(fmaf(di, r.z, b4.z), 0.0f);
        pl[3] = fmaxf(fmaf(di, r.w, b4.w), 0.0f);
    }
    __syncthreads();

    // energy GEMM: row = lane, cols [c0, c0+16) per wave, W via s_load
    const int c0 = __builtin_amdgcn_readfirstlane(w * 16);
    const float* Wp = Wa + c0;

    float acc[16];
#pragma unroll
    for (int cc = 0; cc < 16; ++cc) acc[cc] = 0.0f;

#pragma unroll
    for (int k = 0; k < HD; ++k) {
        float xk = lhx[lane * 65 + k];
#pragma unroll
        for (int cc = 0; cc < 16; ++cc)
            acc[cc] = fmaf(xk, Wp[k * HD + cc], acc[cc]);
    }

    // partial score = sum_cc tanh(acc)*v[c0+cc]  (v via s_load, uniform);
    // inline fast_tanh (no ocml call), 4 independent partials
    float p0 = 0.0f, p1 = 0.0f, p2 = 0.0f, p3 = 0.0f;
#pragma unroll
    for (int cc = 0; cc < 16; cc += 4) {
        p0 = fmaf(fast_tanh(acc[cc + 0]), vvec[c0 + cc + 0], p0);
        p1 = fmaf(fast_tanh(acc[cc + 1]), vvec[c0 + cc + 1], p1);
        p2 = fmaf(fast_tanh(acc[cc + 2]), vvec[c0 + cc + 2], p2);
        p3 = fmaf(fast_tanh(acc[cc + 3]), vvec[c0 + cc + 3], p3);
    }
    sp[w][lane] = (p0 + p1) + (p2 + p3);
    __syncthreads();

    // write h3 rows (normal store -> L3-resident for k_pool)
#pragma unroll
    for (int i = 0; i < 16; ++i) {
        int r = i * 4 + w;
        hout[(size_t)(r0 + r) * HD + lane] = lhx[r * 65 + lane];
    }

    if (w == 0) {
        float s = sp[0][lane] + sp[1][lane] + sp[2][lane] + sp[3][lane];
        sout[r0 + lane] = s;
    }
}

// ---------------- softmax + pool + linear (1 wave per graph) ----------------
__global__ __launch_bounds__(256) void k_pool(const float* __restrict__ h3,
                                              const float* __restrict__ s,
                                              const float* __restrict__ Wl,
                                              const float* __restrict__ bl,
                                              float* __restrict__ out,
                                              float* __restrict__ lw) {
    __shared__ float lds_Wl[128 * 32];
    __shared__ float lds_p[4][128];
    const int t = threadIdx.x;
    const int lane = t & 63;
    const int wid = t >> 6;

#pragma unroll
    for (int i = 0; i < 16; ++i) lds_Wl[t + i * 256] = Wl[t + i * 256];
    __syncthreads();

    const int g = blockIdx.x * 4 + wid;

    // softmax over the 12 lead scores (lanes >=12 padded)
    float sv = (lane < LEADS) ? s[g * LEADS + lane] : -1e30f;
    float m = sv;
#pragma unroll
    for (int off = 32; off >= 1; off >>= 1) m = fmaxf(m, __shfl_xor(m, off));
    // exp(x) = exp2(x*log2e) via hardware v_exp_f32
    float e = (lane < LEADS)
                  ? __builtin_amdgcn_exp2f((sv - m) * 1.4426950408889634f)
                  : 0.0f;
    float sum = e;
#pragma unroll
    for (int off = 32; off >= 1; off >>= 1) sum += __shfl_xor(sum, off);
    float inv = 1.0f / sum;

    if (lane < LEADS) lw[g * LEADS + lane] = e * inv;

    // weighted max/mean pool; lane = feature channel
    float gmax = -1e30f, gsum = 0.0f;
#pragma unroll
    for (int r = 0; r < LEADS; ++r) {
        float wr = __shfl(e, r) * inv;  // graph-uniform weight
        float hv = h3[(size_t)(g * LEADS + r) * HD + lane];
        float wh = hv * wr;
        gmax = fmaxf(gmax, wh);
        gsum += wh;
    }
    lds_p[wid][lane] = gmax;
    lds_p[wid][64 + lane] = gsum * (1.0f / 12.0f);

    int o = lane & 31, half = lane >> 5;
    float acc2 = 0.0f;
#pragma unroll
    for (int k = 0; k < 64; ++k) {
        int kk = half * 64 + k;
        acc2 = fmaf(lds_p[wid][kk], lds_Wl[kk * 32 + o], acc2);
    }
    acc2 += __shfl_xor(acc2, 32);
    if (lane < 32) out[g * 32 + lane] = fmaxf(acc2 + bl[lane], 0.0f);
}

// ---------------- launch ----------------
extern "C" void kernel_launch(void* const* d_in, const int* in_sizes, int n_in,
                              void* d_out, int out_size, void* d_ws, size_t ws_size,
                              hipStream_t stream) {
    const float* x  = (const float*)d_in[0];
    const int* ei   = (const int*)d_in[1];
    const int* src  = ei;
    const int* dst  = ei + N_EDGES;
    const float* W1 = (const float*)d_in[3];
    const float* b1 = (const float*)d_in[4];
    const float* W2 = (const float*)d_in[5];
    const float* b2 = (const float*)d_in[6];
    const float* W3 = (const float*)d_in[7];
    const float* b3 = (const float*)d_in[8];
    const float* Wa = (const float*)d_in[9];
    const float* vv = (const float*)d_in[10];
    const float* Wl = (const float*)d_in[11];
    const float* bl = (const float*)d_in[12];

    float* out = (float*)d_out;
    float* lw  = out + (size_t)NUM_GRAPHS * 32;

    float* dinv = (float*)d_ws;                       // N f32
    int* cnt    = (int*)(dinv + N_NODES);             // N
    int* offs   = cnt + N_NODES;                      // N
    int* bsum   = offs + N_NODES;                     // 1024
    int* eidx   = bsum + 1024;                        // E
    float* T    = (float*)(eidx + N_EDGES);           // N*64
    float* Hb   = T + (size_t)N_NODES * HD;           // N*64
    float* S    = Hb + (size_t)N_NODES * HD;          // N (attention scores)
    // rank aliases T: T is first written by k_gemm, strictly after k_fill
    // consumed rank (in-order stream).
    int* rank   = (int*)T;                            // E (aliased)

    const int gN = (N_NODES + 255) / 256;
    const int gE = (N_EDGES + 255) / 256;

    k_zero<<<gN, 256, 0, stream>>>(cnt);
    k_hist<<<gE, 256, 0, stream>>>(dst, cnt, rank);
    k_scan1<<<SCAN_BLOCKS, 256, 0, stream>>>(cnt, offs, bsum, dinv);
    k_scan2<<<1, 256, 0, stream>>>(bsum);
    k_scan3<<<gN, 256, 0, stream>>>(offs, bsum);
    k_fill<<<gE, 256, 0, stream>>>(src, dst, rank, offs, eidx);

    // layer 1 transform: T1 = dinv * (x @ W1)
    k_gemm<128><<<N_NODES / 64, 256, 0, stream>>>(x, W1, dinv, T);
    // fused: h1 = relu(agg(T1)+b1) in LDS; T2 = dinv * (h1 @ W2)
    k_fused<<<N_NODES / 64, 256, 0, stream>>>(T, eidx, offs, cnt, dinv, b1, W2, Hb);
    // fused: h2 = relu(agg(T2)+b2) in LDS; T3 = dinv * (h2 @ W3)
    k_fused<<<N_NODES / 64, 256, 0, stream>>>(Hb, eidx, offs, cnt, dinv, b2, W3, T);
    // fused: h3 = relu(agg(T3)+b3) in LDS; s = tanh(h3@Wa)@v; write h3 + s
    k_fused3<<<N_NODES / 64, 256, 0, stream>>>(T, eidx, offs, cnt, dinv, b3,
                                               Wa, vv, Hb, S);
    // per-graph softmax + pool + linear
    k_pool<<<NUM_GRAPHS / 4, 256, 0, stream>>>(Hb, S, Wl, bl, out, lw);
}